// Round 6
// baseline (177.143 us; speedup 1.0000x reference)
//
#include <hip/hip_runtime.h>
#include <math.h>

// Problem constants (from setup_inputs): B=16, T=8192, N=32, depth=31, 5 ops.
constexpr int N_STACK = 32;
constexpr int DEPTH = 31;
constexpr int NOPS = 5;
constexpr int BLOCK = 256;
constexpr int CH = 8;                      // steps per prefetch chunk
constexpr int NCH = (DEPTH + CH - 1) / CH; // 4 chunks: 8,8,8,7
constexpr int PAD = 44;                    // LDS row pitch (dwords): rows 16B-aligned
                                           // -> conflict-free ds_read_b128 row reads
constexpr int WSLICE = 64 * PAD;           // 2816 dwords (11,264 B) per wave

#define LOG_LIMF 10.0f

// Force x to be materialized in a VGPR here; the result is opaque, so the
// compiler cannot re-sink / rematerialize the producing load at the use site.
#define PIN(x) asm volatile("" : "+v"(x))

typedef float f4v __attribute__((ext_vector_type(4)));

// _clip_log(l) = tanh(l/10)*10, via tanh(x) = (e^{2x}-1)/(e^{2x}+1)
__device__ __forceinline__ float clip_log(float l) {
    float tx = 0.2f * l;                       // 2*(l/10)
    tx = fminf(fmaxf(tx, -80.0f), 80.0f);      // keep exp finite
    float t = __expf(tx);
    return 10.0f * (t - 1.0f) * __builtin_amdgcn_rcpf(t + 1.0f);
}

// add_log_space branch combine. Shared numeric pieces (l_same_c, nlog, zres, bx)
// are computed once outside (they do not depend on signs). sy is +acc for add,
// -acc for sub.
__device__ __forceinline__ void add_ls(float sx, float lx, float sy, float ly,
                                       float l_same_c, float nlog, bool zres, bool bx,
                                       float &s_o, float &l_o)
{
    bool zx = (sx == 0.0f);
    bool zy = (sy == 0.0f);
    bool both = (!zx) && (!zy);
    bool same_sign = (sx * sy > 0.0f);
    bool same_br = both && same_sign;
    bool opp_br  = both && !same_sign;

    float s = 0.0f, l = 0.0f;          // default: both zero
    if ((!zx) && zy) { s = sx; l = lx; }
    if (zx && (!zy)) { s = sy; l = ly; }
    if (same_br) { s = (sx > 0.0f) ? 1.0f : -1.0f; l = l_same_c; }
    if (opp_br)  { s = zres ? 0.0f : (bx ? sx : sy); l = nlog; }
    s_o = s;
    l_o = clip_log(l);                 // reference clips l_out on return
}

// ---- wave-coalesced chunk movement --------------------------------------
// A wave's 64 op rows are contiguous: 64 x 155 dwords. A chunk is columns
// [40c, 40c+40) of those rows. Flat chunk index f = 40*r + w (r=row, w=word);
// lane loads f = lane + 64*i  -> 64 CONSECUTIVE dwords per instruction
// (~5 cache-line lookups instead of 64). Global dword = f + 115*r + 40*c.
// f/40 is a compile-time-divisor magic-mul (2-3 VALU), i is compile-time.

__device__ __forceinline__ void load_chunk40(const float* __restrict__ wop,
                                             int lane, int c, float* g) {
#pragma unroll
    for (int i = 0; i < 40; ++i) {
        int f = lane + 64 * i;
        int r = f / 40;
        g[i] = wop[f + 115 * r + 40 * c];
    }
}
__device__ __forceinline__ void load_chunk35(const float* __restrict__ wop,
                                             int lane, float* g) {
    // last chunk: words 120..154 (35 per row), flat over 64*35 dwords
#pragma unroll
    for (int i = 0; i < 35; ++i) {
        int f = lane + 64 * i;
        int r = f / 35;
        g[i] = wop[f + 120 * r + 120];
    }
}
// LDS transpose-in: addr = PAD*r + w = f + (PAD-40)*r. Write banks =
// (lane + 4r) % 32 -> <=2-way (free, m136).
__device__ __forceinline__ void lds_put40(float* wl, int lane, const float* g) {
#pragma unroll
    for (int i = 0; i < 40; ++i) {
        int f = lane + 64 * i;
        int r = f / 40;
        wl[f + (PAD - 40) * r] = g[i];
    }
}
__device__ __forceinline__ void lds_put35(float* wl, int lane, const float* g) {
#pragma unroll
    for (int i = 0; i < 35; ++i) {
        int f = lane + 64 * i;
        int r = f / 35;
        wl[f + (PAD - 35) * r] = g[i];
    }
}
// LDS transpose-out: lane reads ITS row (PAD*lane, 16B-aligned) as 10 b128.
// Start banks (12*lane)%32 sweep all 32 banks per 8 lanes -> conflict-free.
// (For the 35-word last chunk, dwords 35..39 are stale pad garbage; the
// compute guard k<DEPTH never consumes probs past word 34.)
__device__ __forceinline__ void lds_get(const float* wl, int lane, float* cur) {
    const f4v* rp = reinterpret_cast<const f4v*>(wl + PAD * lane);
#pragma unroll
    for (int q = 0; q < 10; ++q) {
        f4v t = rp[q];
        cur[4*q+0] = t[0]; cur[4*q+1] = t[1];
        cur[4*q+2] = t[2]; cur[4*q+3] = t[3];
    }
}

// Grid is hard-capped at 2 waves/SIMD (131072 thr = 2048 waves on 1024 SIMDs).
// Compute structure/schedule identical to the proven 49.6us kernel (R0).
// ONE structural change: op chunks are loaded wave-coalesced and transposed
// through a wave-private LDS slice (no barriers needed); per-step probs are
// STILL consumed from registers (cur[40], refilled once per chunk boundary).
// Per-CU TA lane-line-lookups for ops drop ~79k -> ~6k cycles.
__global__ __launch_bounds__(BLOCK)
__attribute__((amdgpu_waves_per_eu(2, 2)))
void stack_fold_kernel(const float* __restrict__ sgn,
                       const float* __restrict__ logm,
                       const float* __restrict__ ops,
                       float* __restrict__ out, int n)
{
    __shared__ float lds[4 * WSLICE];          // 45,056 B

    const int tid = threadIdx.x;
    const int id  = blockIdx.x * BLOCK + tid;
    if (id >= n) return;
    const int lane = tid & 63;
    float* wl = lds + (tid >> 6) * WSLICE;

    // Per-thread contiguous slices; id*128 bytes => float4 aligned.
    const float4* sg4 = reinterpret_cast<const float4*>(sgn  + (size_t)id * N_STACK);
    const float4* lg4 = reinterpret_cast<const float4*>(logm + (size_t)id * N_STACK);
    // Wave's op region: 64 contiguous rows of 155 floats (wave-uniform base).
    const float* wop = ops + (size_t)(blockIdx.x * BLOCK + (tid & ~63)) * (DEPTH * NOPS);

    // ---- issue chunk-0 coalesced loads + all stack loads ----
    float g[40];
    load_chunk40(wop, lane, 0, g);

    float s_arr[N_STACK], l_arr[N_STACK];
#pragma unroll
    for (int i = 0; i < N_STACK / 4; ++i) {
        float4 a = sg4[i];
        float4 b = lg4[i];
        s_arr[4*i+0] = a.x; s_arr[4*i+1] = a.y; s_arr[4*i+2] = a.z; s_arr[4*i+3] = a.w;
        l_arr[4*i+0] = b.x; l_arr[4*i+1] = b.y; l_arr[4*i+2] = b.z; l_arr[4*i+3] = b.w;
    }
#pragma unroll
    for (int i = 0; i < N_STACK; ++i) { PIN(s_arr[i]); PIN(l_arr[i]); }

    // Suffix sum-of-squares of ORIGINAL logs, positions 0..30 (top excluded).
    float S = 0.0f;
#pragma unroll
    for (int i = 0; i < N_STACK - 1; ++i) S = fmaf(l_arr[i], l_arr[i], S);

    // Accumulator = top of stack.
    float as_ = s_arr[N_STACK - 1];
    float al  = l_arr[N_STACK - 1];

    // ---- boundary 0: g(chunk0) -> LDS -> cur; issue chunk-1 loads ----
#pragma unroll
    for (int i = 0; i < 40; ++i) PIN(g[i]);    // vmcnt lands here
    lds_put40(wl, lane, g);
    load_chunk40(wop, lane, 1, g);             // chunk-1 in flight under chunk-0 compute
    float cur[40];
    lds_get(wl, lane, cur);
#pragma unroll
    for (int i = 0; i < 40; ++i) PIN(cur[i]);  // lgkmcnt lands here

#pragma unroll
    for (int c = 0; c < NCH; ++c) {
#pragma unroll
        for (int j = 0; j < CH; ++j) {
            const int k = c * CH + j;
            if (k < DEPTH) {
                float ss = s_arr[N_STACK - 2 - k];   // sec (original input)
                float sl = l_arr[N_STACK - 2 - k];

                float p0 = cur[NOPS*j + 0];
                float p1 = cur[NOPS*j + 1];
                float p2 = cur[NOPS*j + 2];
                float p3 = cur[NOPS*j + 3];
                float p4 = cur[NOPS*j + 4];

                // ---- shared add/sub numeric core (sign-independent) ----
                float d = sl - al;
                float mx = fmaxf(sl, al);
                float lse = mx + __logf(1.0f + __expf(-fabsf(d)));   // logaddexp
                float l_same_c = clip_log(lse);

                bool bx = (sl >= al);                 // bigger_is_x
                float big    = bx ? sl : al;
                float small_ = bx ? al : sl;
                float delta = fminf(fmaxf(small_ - big, -LOG_LIMF), -0.001f);
                float diff = __logf(1.0f - __expf(delta));           // log1p(-exp(delta))
                bool zres = (small_ == big);
                float nlog = zres ? 0.0f : (big + diff);

                // ---- add / sub branch combines ----
                float s_add, l_add, s_sub, l_sub;
                add_ls(ss, sl,  as_, al, l_same_c, nlog, zres, bx, s_add, l_add);
                add_ls(ss, sl, -as_, al, l_same_c, nlog, zres, bx, s_sub, l_sub);

                // ---- mul / div ----
                float sm   = ss * as_;
                float lmul = clip_log(sl + al);
                float ldiv = clip_log(sl - al);

                // ---- soft mix over [add, sub, mul, div, identity(sec)] ----
                float rs = p0 * s_add + p1 * s_sub + (p2 + p3) * sm + p4 * ss;
                float rl = p0 * l_add + p1 * l_sub + p2 * lmul + p3 * ldiv + p4 * sl;

                // ---- RMS rescale: slice = original logs 0..30-k ++ rl (cs = 32-k)
                const float inv_cs = 1.0f / (float)(N_STACK - k);    // compile-time
                float ms = fmaf(rl, rl, S) * inv_cs + 1e-6f;
                float scale = fminf(10.0f * __builtin_amdgcn_rsqf(ms), 1.0f);
                rl = rl * scale;

                // retire original element 30-k from the suffix sum
                S = fmaf(-sl, sl, S);

                as_ = rs;
                al  = rl;
            }
        }

        // ---- chunk boundary: vmcnt lands behind ~8 steps of ALU; wave-private
        //      LDS slice, single-buffered (all chunk-c LDS reads completed at
        //      the PREVIOUS boundary into cur registers) — no barrier needed.
        if (c + 1 < NCH) {
            const int W = (c + 1 < NCH - 1) ? 40 : 35;
#pragma unroll
            for (int i = 0; i < 40; ++i) if (i < W) PIN(g[i]);
            if (c + 1 < NCH - 1) lds_put40(wl, lane, g);
            else                 lds_put35(wl, lane, g);
            if (c + 2 < NCH) {
                if (c + 2 < NCH - 1) load_chunk40(wop, lane, c + 2, g);
                else                 load_chunk35(wop, lane, g);
            }
            lds_get(wl, lane, cur);
#pragma unroll
            for (int i = 0; i < 40; ++i) PIN(cur[i]);
        }
    }

    // Output: (2, B, T) flattened — [0..n) = sign, [n..2n) = log
    out[id]     = as_;
    out[n + id] = al;
}

extern "C" void kernel_launch(void* const* d_in, const int* in_sizes, int n_in,
                              void* d_out, int out_size, void* d_ws, size_t ws_size,
                              hipStream_t stream) {
    const float* sgn  = (const float*)d_in[0];
    const float* logm = (const float*)d_in[1];
    const float* ops  = (const float*)d_in[2];
    float* out = (float*)d_out;

    int n = in_sizes[0] / N_STACK;   // B*T = 131072
    int blocks = (n + BLOCK - 1) / BLOCK;
    stack_fold_kernel<<<blocks, BLOCK, 0, stream>>>(sgn, logm, ops, out, n);
}